// Round 7
// baseline (216.846 us; speedup 1.0000x reference)
//
#include <hip/hip_runtime.h>
#include <hip/hip_bf16.h>

// GCNConv: out = A @ (X @ W)
// Stage 0: WT[n][k] = bf16(W[k][n])                         (prep kernel, d_ws)
// Stage 1: Xp = bf16(X @ W) via MFMA 16x16x32.  B (=WT) staged ONCE in LDS for
//          all 256 k; A fragments loaded global->reg; K-loop has NO barriers.
// Stage 2: out[i,:] = sum_e Xp[colx[e],:]  one wave/node, degree-16 fast path
//
// DIAGNOSTIC ROUND: gemm_xw launched 6x (5 redundant, idempotent rewrites of
// identical Xp bytes) to measure warm gemm duration as (dur - 146.3)/5.
// spmm reverted to the proven round-4 single-pass form.

constexpr int D_IN  = 256;
constexpr int D_OUT = 128;
constexpr int BM  = 128;
constexpr int BK  = 32;
constexpr int LDB = 296;  // shorts/row: 592 B = 16B-aligned, 20-dword bank shift
                          // -> ds_read_b128 across 16 rows is conflict-free

using short8  = __attribute__((ext_vector_type(8))) short;
using float4v = __attribute__((ext_vector_type(4))) float;

__device__ inline ushort f2bf(float f) {
    unsigned u = __float_as_uint(f);
    u = (u + 0x7FFFu + ((u >> 16) & 1u)) >> 16;   // RNE
    return (ushort)u;
}

__device__ inline uint pk2bf(float lo, float hi) {
    float2 t; t.x = lo; t.y = hi;
    __hip_bfloat162 b = __float22bfloat162_rn(t);   // v_cvt_pk_bf16_f32
    return *(uint*)&b;
}

// W[k][n] fp32 -> WT[n][k] bf16  (128 rows x 256 cols)
__global__ __launch_bounds__(256) void prep_wt(const float* __restrict__ W,
                                               ushort* __restrict__ WT) {
    int id = blockIdx.x * 256 + threadIdx.x;   // 32768 total
    int nn = id >> 8;        // 0..127
    int k  = id & 255;       // 0..255
    WT[nn * 256 + k] = f2bf(W[k * D_OUT + nn]);
}

__global__ __launch_bounds__(256, 2) void gemm_xw(const float* __restrict__ X,
                                                  const ushort* __restrict__ WT,
                                                  ushort* __restrict__ Xp, int n) {
    __shared__ ushort Bs[D_OUT * LDB];   // 128 x 296 shorts = 74 KB -> 2 blk/CU
    const int tid  = threadIdx.x;
    const int wave = tid >> 6;
    const int lane = tid & 63;
    const int quad = lane >> 4;
    const int l16  = lane & 15;
    const int row0 = blockIdx.x * BM;

    // ---- stage ALL of B once: WT[128][256] -> Bs[128][LDB] ----
#pragma unroll
    for (int i = 0; i < 16; ++i) {
        int idx = i * 256 + tid;       // 0..4095 short8 chunks
        int r   = idx >> 5;            // row 0..127
        int ch  = idx & 31;            // chunk 0..31
        short8 v = *(const short8*)(WT + r * 256 + ch * 8);
        *(short8*)(&Bs[r * LDB + ch * 8]) = v;   // 16B aligned (592r + 16ch)
    }
    __syncthreads();                   // the ONLY barrier in this kernel

    // A rows owned by this lane (clamped; epilogue guards real writes)
    int r0 = row0 + wave * 32 + l16;      if (r0 > n - 1) r0 = n - 1;
    int r1 = row0 + wave * 32 + 16 + l16; if (r1 > n - 1) r1 = n - 1;
    const float* xr0 = X + (size_t)r0 * D_IN + quad * 8;
    const float* xr1 = X + (size_t)r1 * D_IN + quad * 8;

    float4v acc[2][8];
#pragma unroll
    for (int i = 0; i < 2; ++i)
#pragma unroll
        for (int t = 0; t < 8; ++t) acc[i][t] = (float4v){0.f, 0.f, 0.f, 0.f};

    // Barrier-free K-loop: per step, A-frags come straight from global memory
    // (8 contiguous floats per lane per frag); B-frags from resident LDS.
#pragma unroll
    for (int k0 = 0; k0 < D_IN; k0 += BK) {
        float4 u0 = *(const float4*)(xr0 + k0);
        float4 u1 = *(const float4*)(xr0 + k0 + 4);
        float4 w0 = *(const float4*)(xr1 + k0);
        float4 w1 = *(const float4*)(xr1 + k0 + 4);
        union { short8 s; uint u[4]; } A0, A1;
        A0.u[0] = pk2bf(u0.x, u0.y);  A0.u[1] = pk2bf(u0.z, u0.w);
        A0.u[2] = pk2bf(u1.x, u1.y);  A0.u[3] = pk2bf(u1.z, u1.w);
        A1.u[0] = pk2bf(w0.x, w0.y);  A1.u[1] = pk2bf(w0.z, w0.w);
        A1.u[2] = pk2bf(w1.x, w1.y);  A1.u[3] = pk2bf(w1.z, w1.w);
#pragma unroll
        for (int t = 0; t < 8; ++t) {
            // B fragment: lane holds B[k = k0 + quad*8 + j][nn = t*16 + l16]
            short8 b = *(const short8*)(&Bs[(t * 16 + l16) * LDB + k0 + quad * 8]);
            acc[0][t] = __builtin_amdgcn_mfma_f32_16x16x32_bf16(A0.s, b, acc[0][t], 0, 0, 0);
            acc[1][t] = __builtin_amdgcn_mfma_f32_16x16x32_bf16(A1.s, b, acc[1][t], 0, 0, 0);
        }
    }

    // Epilogue: C/D layout col = l16, row = quad*4 + reg. Plain stores: Xp is
    // re-read 16x by the next dispatch -- keep it resident in L2.
#pragma unroll
    for (int rt = 0; rt < 2; ++rt) {
#pragma unroll
        for (int t = 0; t < 8; ++t) {
#pragma unroll
            for (int r = 0; r < 4; ++r) {
                int row = row0 + wave * 32 + rt * 16 + quad * 4 + r;
                if (row < n)
                    Xp[(size_t)row * D_OUT + t * 16 + l16] = f2bf(acc[rt][t][r]);
            }
        }
    }
}

// One wave per node; lane covers 2 of 128 cols (4B bf16x2 per edge, coalesced).
// Degree-16 fast path: 16 index loads, then 16 gathers all in flight.
__global__ __launch_bounds__(256) void spmm_agg(const ushort* __restrict__ Xp,
                                                const int* __restrict__ rowp,
                                                const int* __restrict__ colx,
                                                float* __restrict__ out, int n) {
    const int node = blockIdx.x * 4 + (threadIdx.x >> 6);
    const int lane = threadIdx.x & 63;
    if (node >= n) return;
    const int e0 = rowp[node];
    const int e1 = rowp[node + 1];
    const ushort* src = Xp + lane * 2;
    float s0 = 0.f, s1 = 0.f;
    if (e1 - e0 == 16) {
        int c[16];
#pragma unroll
        for (int i = 0; i < 16; ++i) c[i] = colx[e0 + i];   // wave-uniform -> s_load
        uint v[16];
#pragma unroll
        for (int i = 0; i < 16; ++i)
            v[i] = *(const uint*)(src + (size_t)c[i] * D_OUT);  // 16 gathers in flight
#pragma unroll
        for (int i = 0; i < 16; ++i) {
            s0 += __uint_as_float(v[i] << 16);
            s1 += __uint_as_float(v[i] & 0xFFFF0000u);
        }
    } else {
        for (int e = e0; e < e1; ++e) {
            uint v = *(const uint*)(src + (size_t)colx[e] * D_OUT);
            s0 += __uint_as_float(v << 16);
            s1 += __uint_as_float(v & 0xFFFF0000u);
        }
    }
    // Non-temporal: out is write-once-never-read (25.6 MB stream); keep it from
    // evicting the 12.8 MB Xp gather working set out of per-XCD L2.
    union { float2 f; double d; } u;
    u.f.x = s0; u.f.y = s1;
    __builtin_nontemporal_store(u.d, (double*)(out + (size_t)node * D_OUT + lane * 2));
}

extern "C" void kernel_launch(void* const* d_in, const int* in_sizes, int n_in,
                              void* d_out, int out_size, void* d_ws, size_t ws_size,
                              hipStream_t stream) {
    const float* X    = (const float*)d_in[0];
    const float* W    = (const float*)d_in[1];
    const int*   rowp = (const int*)d_in[2];
    const int*   colx = (const int*)d_in[3];
    float*       out  = (float*)d_out;

    ushort* WT = (ushort*)d_ws;                       // 128*256*2 = 64 KB
    ushort* Xp = (ushort*)((char*)d_ws + 65536);      // n*128*2 = 12.8 MB

    const int n = in_sizes[0] / D_IN;                 // 50000

    prep_wt<<<dim3(128), dim3(256), 0, stream>>>(W, WT);
    // DIAGNOSTIC: 6 identical gemm launches (idempotent). gemm_warm dur =
    // (this round's dur_us - 146.3) / 5. Revert to 1 launch next round.
    for (int rep = 0; rep < 6; ++rep)
        gemm_xw<<<dim3((n + BM - 1) / BM), dim3(256), 0, stream>>>(X, WT, Xp, n);
    spmm_agg<<<dim3((n + 3) / 4), dim3(256), 0, stream>>>(Xp, rowp, colx, out, n);
}

// Round 8
// 144.597 us; speedup vs baseline: 1.4997x; 1.4997x over previous
//
#include <hip/hip_runtime.h>
#include <hip/hip_bf16.h>

// GCNConv: out = A @ (X @ W)
// Stage 0: WT[n][k] = bf16(W[k][n])                         (prep kernel, d_ws)
// Stage 1: Xp = bf16(X @ W) via MFMA 16x16x32.  B (=WT) staged ONCE in LDS for
//          all 256 k; A fragments loaded global->reg; K-loop has NO barriers.
// Stage 2: out[i,:] = sum_e Xp[colx[e],:]  -- 2 passes x 64 cols. Each pass's
//          gather slice is 128 B = exactly one cache line per row (no
//          over-fetch, unlike round-6's 64 B slices), and the per-pass line
//          working set is 6.4 MB vs 12.8 MB single-pass -> higher per-XCD L2
//          residency for the 16x-reused rows.

constexpr int D_IN  = 256;
constexpr int D_OUT = 128;
constexpr int BM  = 128;
constexpr int BK  = 32;
constexpr int LDB = 296;  // shorts/row: 592 B = 16B-aligned, 20-dword bank shift

using short8  = __attribute__((ext_vector_type(8))) short;
using float4v = __attribute__((ext_vector_type(4))) float;

__device__ inline ushort f2bf(float f) {
    unsigned u = __float_as_uint(f);
    u = (u + 0x7FFFu + ((u >> 16) & 1u)) >> 16;   // RNE
    return (ushort)u;
}

__device__ inline uint pk2bf(float lo, float hi) {
    float2 t; t.x = lo; t.y = hi;
    __hip_bfloat162 b = __float22bfloat162_rn(t);   // v_cvt_pk_bf16_f32
    return *(uint*)&b;
}

// W[k][n] fp32 -> WT[n][k] bf16  (128 rows x 256 cols)
__global__ __launch_bounds__(256) void prep_wt(const float* __restrict__ W,
                                               ushort* __restrict__ WT) {
    int id = blockIdx.x * 256 + threadIdx.x;   // 32768 total
    int nn = id >> 8;        // 0..127
    int k  = id & 255;       // 0..255
    WT[nn * 256 + k] = f2bf(W[k * D_OUT + nn]);
}

__global__ __launch_bounds__(256, 2) void gemm_xw(const float* __restrict__ X,
                                                  const ushort* __restrict__ WT,
                                                  ushort* __restrict__ Xp, int n) {
    __shared__ ushort Bs[D_OUT * LDB];   // 128 x 296 shorts = 74 KB -> 2 blk/CU
    const int tid  = threadIdx.x;
    const int wave = tid >> 6;
    const int lane = tid & 63;
    const int quad = lane >> 4;
    const int l16  = lane & 15;
    const int row0 = blockIdx.x * BM;

    // ---- stage ALL of B once: WT[128][256] -> Bs[128][LDB] ----
#pragma unroll
    for (int i = 0; i < 16; ++i) {
        int idx = i * 256 + tid;       // 0..4095 short8 chunks
        int r   = idx >> 5;            // row 0..127
        int ch  = idx & 31;            // chunk 0..31
        short8 v = *(const short8*)(WT + r * 256 + ch * 8);
        *(short8*)(&Bs[r * LDB + ch * 8]) = v;   // 16B aligned (592r + 16ch)
    }
    __syncthreads();                   // the ONLY barrier in this kernel

    // A rows owned by this lane (clamped; epilogue guards real writes)
    int r0 = row0 + wave * 32 + l16;      if (r0 > n - 1) r0 = n - 1;
    int r1 = row0 + wave * 32 + 16 + l16; if (r1 > n - 1) r1 = n - 1;
    const float* xr0 = X + (size_t)r0 * D_IN + quad * 8;
    const float* xr1 = X + (size_t)r1 * D_IN + quad * 8;

    float4v acc[2][8];
#pragma unroll
    for (int i = 0; i < 2; ++i)
#pragma unroll
        for (int t = 0; t < 8; ++t) acc[i][t] = (float4v){0.f, 0.f, 0.f, 0.f};

    // Barrier-free K-loop: per step, A-frags come straight from global memory
    // (8 contiguous floats per lane per frag); B-frags from resident LDS.
#pragma unroll
    for (int k0 = 0; k0 < D_IN; k0 += BK) {
        float4 u0 = *(const float4*)(xr0 + k0);
        float4 u1 = *(const float4*)(xr0 + k0 + 4);
        float4 w0 = *(const float4*)(xr1 + k0);
        float4 w1 = *(const float4*)(xr1 + k0 + 4);
        union { short8 s; uint u[4]; } A0, A1;
        A0.u[0] = pk2bf(u0.x, u0.y);  A0.u[1] = pk2bf(u0.z, u0.w);
        A0.u[2] = pk2bf(u1.x, u1.y);  A0.u[3] = pk2bf(u1.z, u1.w);
        A1.u[0] = pk2bf(w0.x, w0.y);  A1.u[1] = pk2bf(w0.z, w0.w);
        A1.u[2] = pk2bf(w1.x, w1.y);  A1.u[3] = pk2bf(w1.z, w1.w);
#pragma unroll
        for (int t = 0; t < 8; ++t) {
            // B fragment: lane holds B[k = k0 + quad*8 + j][nn = t*16 + l16]
            short8 b = *(const short8*)(&Bs[(t * 16 + l16) * LDB + k0 + quad * 8]);
            acc[0][t] = __builtin_amdgcn_mfma_f32_16x16x32_bf16(A0.s, b, acc[0][t], 0, 0, 0);
            acc[1][t] = __builtin_amdgcn_mfma_f32_16x16x32_bf16(A1.s, b, acc[1][t], 0, 0, 0);
        }
    }

    // Epilogue: C/D layout col = l16, row = quad*4 + reg. Plain stores: Xp is
    // re-read 16x by the next dispatch -- keep it resident in L2.
#pragma unroll
    for (int rt = 0; rt < 2; ++rt) {
#pragma unroll
        for (int t = 0; t < 8; ++t) {
#pragma unroll
            for (int r = 0; r < 4; ++r) {
                int row = row0 + wave * 32 + rt * 16 + quad * 4 + r;
                if (row < n)
                    Xp[(size_t)row * D_OUT + t * 16 + l16] = f2bf(acc[rt][t][r]);
            }
        }
    }
}

// Column-blocked aggregation pass: cols [col0, col0+64), col0 in {0, 64}.
// 2 nodes per wave: 32-lane group s handles node = blk*8 + wave*2 + s;
// lane covers 2 of the 64 pass-cols. Per gather: 128 B = exactly one cache
// line per row (row stride 256 B, col0 line-aligned) -> zero over-fetch.
// Per-pass line working set = n * 128 B = 6.4 MB (vs 12.8 single-pass).
__global__ __launch_bounds__(256) void spmm_agg64(const ushort* __restrict__ Xp,
                                                  const int* __restrict__ rowp,
                                                  const int* __restrict__ colx,
                                                  float* __restrict__ out, int n,
                                                  int col0) {
    const int wave = threadIdx.x >> 6;
    const int lane = threadIdx.x & 63;
    const int sub  = lane >> 5;          // 0..1: node within wave
    const int l32  = lane & 31;          // col pair within 64-col slice
    const int node = blockIdx.x * 8 + wave * 2 + sub;
    if (node >= n) return;
    const int e0 = rowp[node];
    const int e1 = rowp[node + 1];
    const ushort* src = Xp + col0 + l32 * 2;
    float s0 = 0.f, s1 = 0.f;
    if (e1 - e0 == 16) {
        int c[16];
#pragma unroll
        for (int i = 0; i < 16; ++i) c[i] = colx[e0 + i];   // bcast within group
        uint v[16];
#pragma unroll
        for (int i = 0; i < 16; ++i)
            v[i] = *(const uint*)(src + (size_t)c[i] * D_OUT);  // 16 in flight
#pragma unroll
        for (int i = 0; i < 16; ++i) {
            s0 += __uint_as_float(v[i] << 16);
            s1 += __uint_as_float(v[i] & 0xFFFF0000u);
        }
    } else {
        for (int e = e0; e < e1; ++e) {
            uint v = *(const uint*)(src + (size_t)colx[e] * D_OUT);
            s0 += __uint_as_float(v << 16);
            s1 += __uint_as_float(v & 0xFFFF0000u);
        }
    }
    // 32 lanes x 8 B = 256 B contiguous per node per pass, line-aligned.
    // nt: out is write-once; don't evict the pass's Xp slice from L2.
    union { float2 f; double d; } u;
    u.f.x = s0; u.f.y = s1;
    __builtin_nontemporal_store(
        u.d, (double*)(out + (size_t)node * D_OUT + col0 + l32 * 2));
}

extern "C" void kernel_launch(void* const* d_in, const int* in_sizes, int n_in,
                              void* d_out, int out_size, void* d_ws, size_t ws_size,
                              hipStream_t stream) {
    const float* X    = (const float*)d_in[0];
    const float* W    = (const float*)d_in[1];
    const int*   rowp = (const int*)d_in[2];
    const int*   colx = (const int*)d_in[3];
    float*       out  = (float*)d_out;

    ushort* WT = (ushort*)d_ws;                       // 128*256*2 = 64 KB
    ushort* Xp = (ushort*)((char*)d_ws + 65536);      // n*128*2 = 12.8 MB

    const int n = in_sizes[0] / D_IN;                 // 50000

    prep_wt<<<dim3(128), dim3(256), 0, stream>>>(W, WT);
    gemm_xw<<<dim3((n + BM - 1) / BM), dim3(256), 0, stream>>>(X, WT, Xp, n);
    // 2 column passes, 64 cols each (one 128-B line per row per pass);
    // sequential in-stream so each pass's 6.4 MB line set stays L2-warm.
    for (int p = 0; p < 2; ++p)
        spmm_agg64<<<dim3((n + 7) / 8), dim3(256), 0, stream>>>(
            Xp, rowp, colx, out, n, p * 64);
}